// Round 13
// baseline (486.793 us; speedup 1.0000x reference)
//
#include <hip/hip_runtime.h>
#include <stdint.h>

// ---- workspace layout (float offsets) ----
#define WS_BN    0u        // A1[64] B1[64] A2[128] B2[128] = 384
#define WS_NR    384u      // nr[32] dr[32]
#define WS_FMAX  448u      // float (atomicMax as int)
#define WS_CTR   449u      // int ticket counter for k5 last-block
#define WS_CNTP  450u      // int[20][10] histogram partials (slot-written, no zero needed)
#define WS_P2F   768u      // [32][8192] f fp32 = 262144 (persistent through k4)
#define WS_X     262912u   // overlay:
#define WS_P1    WS_X                 // conv: [32][64][16][16] = 524288
#define WS_W2T   (WS_X + 524288u)     // conv: [9][64][128]     = 73728
#define WS_L1P   WS_X                 // knn:  [16][32][20096]  = 10289152

typedef float f4v __attribute__((ext_vector_type(4)));

__device__ __forceinline__ unsigned sad4(unsigned a, unsigned b, unsigned c) {
#if __has_builtin(__builtin_amdgcn_sad_u8)
  return __builtin_amdgcn_sad_u8(a, b, c);
#else
  unsigned d;
  asm("v_sad_u8 %0, %1, %2, %3" : "=v"(d) : "v"(a), "v"(b), "v"(c));
  return d;
#endif
}

__device__ __forceinline__ unsigned qpack(f4v v, float kq) {
  unsigned q0 = (unsigned)fmaf(v.x, kq, 0.5f);
  unsigned q1 = (unsigned)fmaf(v.y, kq, 0.5f);
  unsigned q2 = (unsigned)fmaf(v.z, kq, 0.5f);
  unsigned q3 = (unsigned)fmaf(v.w, kq, 0.5f);
  return q0 | (q1 << 8) | (q2 << 16) | (q3 << 24);
}

// ---------------- prep: BN fold + zeros | label histogram partials | w2t ----
__global__ __launch_bounds__(256) void prep(
    const int* __restrict__ labels, const float* __restrict__ w2,
    const float* __restrict__ c1b, const float* __restrict__ g1,
    const float* __restrict__ be1, const float* __restrict__ m1,
    const float* __restrict__ v1,
    const float* __restrict__ c2b, const float* __restrict__ g2,
    const float* __restrict__ be2, const float* __restrict__ m2,
    const float* __restrict__ v2,
    float* __restrict__ ws)
{
  int blk = blockIdx.x, tid = threadIdx.x;
  if (blk == 0) {
    if (tid < 64) {
      ws[WS_NR + tid] = 0.f;
      float A = g1[tid] * __frsqrt_rn(v1[tid] + 1e-5f);
      ws[WS_BN + tid] = A;
      ws[WS_BN + 64 + tid] = (c1b[tid] - m1[tid]) * A + be1[tid];
    } else if (tid < 192) {
      int c = tid - 64;
      float A = g2[c] * __frsqrt_rn(v2[c] + 1e-5f);
      ws[WS_BN + 128 + c] = A;
      ws[WS_BN + 256 + c] = (c2b[c] - m2[c]) * A + be2[c];
    } else if (tid == 192) {
      ws[WS_FMAX] = 2.0f;
    } else if (tid == 193) {
      ((int*)ws)[WS_CTR] = 0;
    }
  } else if (blk <= 20) {
    __shared__ int cnt[10];
    if (tid < 10) cnt[tid] = 0;
    __syncthreads();
    int base = (blk - 1) * 1000;
    for (int i = base + tid; i < base + 1000; i += 256)
      atomicAdd(&cnt[labels[i]], 1);
    __syncthreads();
    if (tid < 10) ((int*)(ws + WS_CNTP))[(blk - 1) * 10 + tid] = cnt[tid];
  } else {
    int idx = (blk - 21) * 256 + tid;
    if (idx < 73728) {
      int co = idx / 576, r = idx % 576, ci = r / 9, kk = r % 9;
      ws[WS_W2T + (kk * 64 + ci) * 128 + co] = w2[idx];
    }
  }
}

// ---------------- k2: conv1 + BN + ReLU + 2x2 maxpool ----------------
__global__ __launch_bounds__(256) void k2_conv1(
    const float* __restrict__ x, const float* __restrict__ w1,
    const float* __restrict__ wsc, float* __restrict__ p1)
{
  __shared__ float xs[3 * 34 * 34];
  int tid = threadIdx.x;
  int b = blockIdx.x >> 4, cog = blockIdx.x & 15;

  for (int idx = tid; idx < 3 * 34 * 34; idx += 256) {
    int ci = idx / 1156, r = idx % 1156, yy = r / 34, xc = r % 34;
    int yg = yy - 1, xg = xc - 1;
    float v = 0.f;
    if ((unsigned)yg < 32u && (unsigned)xg < 32u)
      v = x[((b * 3 + ci) * 32 + yg) * 32 + xg];
    xs[idx] = v;
  }
  __syncthreads();

  int py = tid >> 4, px = tid & 15;
  float acc[4][4] = {};
#pragma unroll
  for (int ci = 0; ci < 3; ++ci)
#pragma unroll
    for (int ky = 0; ky < 3; ++ky)
#pragma unroll
      for (int kx = 0; kx < 3; ++kx) {
        const float* xp = &xs[ci * 1156 + (2 * py + ky) * 34 + (2 * px + kx)];
        float i00 = xp[0], i01 = xp[1], i10 = xp[34], i11 = xp[35];
#pragma unroll
        for (int c = 0; c < 4; ++c) {
          float wv = w1[cog * 108 + c * 27 + ci * 9 + ky * 3 + kx];  // uniform -> s_load
          acc[c][0] = fmaf(i00, wv, acc[c][0]);
          acc[c][1] = fmaf(i01, wv, acc[c][1]);
          acc[c][2] = fmaf(i10, wv, acc[c][2]);
          acc[c][3] = fmaf(i11, wv, acc[c][3]);
        }
      }
#pragma unroll
  for (int c = 0; c < 4; ++c) {
    int co = cog * 4 + c;
    float A = wsc[WS_BN + co], B = wsc[WS_BN + 64 + co];
    float v0 = fmaxf(fmaf(acc[c][0], A, B), 0.f);
    float v1 = fmaxf(fmaf(acc[c][1], A, B), 0.f);
    float v2 = fmaxf(fmaf(acc[c][2], A, B), 0.f);
    float v3 = fmaxf(fmaf(acc[c][3], A, B), 0.f);
    float m = fmaxf(fmaxf(v0, v1), fmaxf(v2, v3));
    p1[((b * 64 + co) * 16 + py) * 16 + px] = m;
  }
}

// ---------------- k3: conv2 + BN + ReLU + pool + fused global fmax ----------------
__global__ __launch_bounds__(256) void k3_conv2(
    const float* __restrict__ p1, const float* __restrict__ w2t,
    const float* __restrict__ wsc, float* __restrict__ p2f,
    float* __restrict__ out, float* __restrict__ ws)
{
  __shared__ float in_s[32 * 324];  // 40.5 KB
  __shared__ float pb[4096];        // 16 KB pool buffer
  int tid = threadIdx.x;
  int b = blockIdx.x >> 3, cog = blockIdx.x & 7;
  int y = tid >> 4, xx = tid & 15;

  float acc[16];
#pragma unroll
  for (int c = 0; c < 16; ++c) acc[c] = 0.f;

  for (int h = 0; h < 2; ++h) {
    __syncthreads();
    for (int idx = tid; idx < 10368; idx += 256) {
      int ci = idx / 324, r = idx % 324, yy = r / 18, xc = r % 18;
      int yg = yy - 1, xg = xc - 1;
      float v = 0.f;
      if ((unsigned)yg < 16u && (unsigned)xg < 16u)
        v = p1[((b * 64 + h * 32 + ci) * 16 + yg) * 16 + xg];
      in_s[idx] = v;
    }
    __syncthreads();
    for (int ci = 0; ci < 32; ++ci) {
#pragma unroll
      for (int kk = 0; kk < 9; ++kk) {
        int ky = kk / 3, kx = kk % 3;
        float in = in_s[ci * 324 + (y + ky) * 18 + (xx + kx)];
        const float4* wp = (const float4*)(w2t + ((kk * 64 + h * 32 + ci) * 128 + cog * 16));
        float4 a0 = wp[0], a1 = wp[1], a2 = wp[2], a3 = wp[3];  // uniform -> s_load
        acc[0]  = fmaf(in, a0.x, acc[0]);  acc[1]  = fmaf(in, a0.y, acc[1]);
        acc[2]  = fmaf(in, a0.z, acc[2]);  acc[3]  = fmaf(in, a0.w, acc[3]);
        acc[4]  = fmaf(in, a1.x, acc[4]);  acc[5]  = fmaf(in, a1.y, acc[5]);
        acc[6]  = fmaf(in, a1.z, acc[6]);  acc[7]  = fmaf(in, a1.w, acc[7]);
        acc[8]  = fmaf(in, a2.x, acc[8]);  acc[9]  = fmaf(in, a2.y, acc[9]);
        acc[10] = fmaf(in, a2.z, acc[10]); acc[11] = fmaf(in, a2.w, acc[11]);
        acc[12] = fmaf(in, a3.x, acc[12]); acc[13] = fmaf(in, a3.y, acc[13]);
        acc[14] = fmaf(in, a3.z, acc[14]); acc[15] = fmaf(in, a3.w, acc[15]);
      }
    }
  }
  __syncthreads();
#pragma unroll
  for (int c = 0; c < 16; ++c) {
    int co = cog * 16 + c;
    float v = fmaxf(fmaf(acc[c], wsc[WS_BN + 128 + co], wsc[WS_BN + 256 + co]), 0.f);
    pb[c * 256 + y * 16 + xx] = v;
  }
  __syncthreads();
  if (tid < 64) {
    int py = tid >> 3, px = tid & 7;
    float lmax = 0.f;   // post-ReLU values >= 0
#pragma unroll
    for (int c = 0; c < 16; ++c) {
      const float* q = &pb[c * 256 + (2 * py) * 16 + 2 * px];
      float m = fmaxf(fmaxf(q[0], q[1]), fmaxf(q[16], q[17]));
      int co = cog * 16 + c;
      int fi = b * 8192 + co * 64 + py * 8 + px;
      p2f[fi] = m;
      out[32 + fi] = m;
      lmax = fmaxf(lmax, m);
    }
#pragma unroll
    for (int off = 32; off > 0; off >>= 1) lmax = fmaxf(lmax, __shfl_xor(lmax, off));
    if (tid == 0) atomicMax((int*)(ws + WS_FMAX), __float_as_int(lmax));
  }
}

// ---------------- k4: DIAGNOSTIC x2 — body identical to r12, executed twice --
// Purpose: k4 duration ~2x (~600 us) exceeds the ~400 us harness poison-fills
// so it surfaces as the TOP dispatch in the PMC table (we've had zero k4
// visibility since r9). Reads: VALUBusy >=75% => H1 (v_sad_u8 sub-full-rate,
// VALU-bound); <=50% => H2 (latency/overlap). Deterministic: rep 1 recomputes
// and rewrites identical l1p values.
__global__ __launch_bounds__(256) void k4_knn(
    const float* __restrict__ nbr, const float* __restrict__ p2f,
    const float* __restrict__ wsc, float* __restrict__ l1p)
{
  __shared__ __align__(16) char smem[40960];   // nt 32 KB | ft 8 KB
  char* nt = smem;
  char* ft = smem + 32768;
  const int tid = threadIdx.x;
  const int w = tid >> 6, lane = tid & 63;
  const int b_lane = lane & 3;    // 0..3
  const int n_lane = lane >> 2;   // 0..15
  const int n0 = blockIdx.x * 128;
  const int s = blockIdx.y;
  const float kq = 255.0f / wsc[WS_FMAX];

#pragma unroll 1
  for (int rep = 0; rep < 2; ++rep) {
    __syncthreads();   // protect nt/ft vs previous rep's red-overlay reads

    unsigned acc[8][8];
#pragma unroll
    for (int i = 0; i < 8; ++i)
#pragma unroll
      for (int j = 0; j < 8; ++j) acc[i][j] = 0u;

#pragma unroll 1
    for (int ch = 0; ch < 2; ++ch) {
      const int dc = s * 512 + ch * 256;
      // ---- stage n: wave w stages rows [w*32, +32); 1 row = 1 KB contiguous --
#pragma unroll 8
      for (int k = 0; k < 32; ++k) {
        int row = w * 32 + k;
        int nn = n0 + row; if (nn > 19999) nn = 19999;
        f4v v = __builtin_nontemporal_load(
            (const f4v*)(nbr + (size_t)nn * 8192 + dc + lane * 4));
        int slot = (lane >> 2) ^ (row & 15);
        *(unsigned*)(nt + row * 256 + (slot << 4) + (lane & 3) * 4) = qpack(v, kq);
      }
      // ---- stage f: wave w stages rows [w*8, +8); L2-hot ----
#pragma unroll
      for (int k = 0; k < 8; ++k) {
        int row = w * 8 + k;
        f4v v = *(const f4v*)(p2f + row * 8192 + dc + lane * 4);
        int slot = (lane >> 2) ^ (row & 15);
        *(unsigned*)(ft + row * 256 + (slot << 4) + (lane & 3) * 4) = qpack(v, kq);
      }
      __syncthreads();
      // ---- compute: wave w reads column slots [w*4, +4) ----
#pragma unroll
      for (int g = 0; g < 4; ++g) {
        const int cs = w * 4 + g;
        uint4 fv[8];
#pragma unroll
        for (int i = 0; i < 8; ++i) {
          int row = b_lane + 4 * i;
          fv[i] = *(const uint4*)(ft + row * 256 + ((cs ^ (row & 15)) << 4));
        }
#pragma unroll
        for (int j = 0; j < 8; ++j) {
          int row = n_lane + 16 * j;
          uint4 nv = *(const uint4*)(nt + row * 256 + ((cs ^ (row & 15)) << 4));
#pragma unroll
          for (int i = 0; i < 8; ++i) {
            unsigned t0 = sad4(fv[i].x, nv.x, acc[i][j]);
            t0 = sad4(fv[i].y, nv.y, t0);
            t0 = sad4(fv[i].z, nv.z, t0);
            acc[i][j] = sad4(fv[i].w, nv.w, t0);
          }
        }
      }
      __syncthreads();
    }

    // cross-wave reduce, 2 halves of 16 b-rows (32 KB overlay aliases tiles)
    unsigned* red = (unsigned*)smem;
#pragma unroll
    for (int r = 0; r < 2; ++r) {
      __syncthreads();
#pragma unroll
      for (int ii = 0; ii < 4; ++ii) {
#pragma unroll
        for (int j = 0; j < 8; ++j) {
          int b16 = b_lane + 4 * ii;            // 0..15 within this half
          int n = n_lane + 16 * j;
          red[(b16 * 128 + n) * 4 + w] = acc[r * 4 + ii][j];
        }
      }
      __syncthreads();
#pragma unroll
      for (int k = 0; k < 8; ++k) {
        int e = k * 256 + tid;                  // 0..2047
        uint4 v = *(const uint4*)(red + e * 4);
        int b = 16 * r + (e >> 7), n = e & 127;
        l1p[(s * 32 + b) * 20096 + n0 + n] = (float)(v.x + v.y + v.z + v.w);
      }
    }
  }
}

// ---------------- k5: reduce splits, exp-weight, mask, last-block finalize ----
__global__ __launch_bounds__(256) void k5_final(
    const float* __restrict__ l1p, const int* __restrict__ labels,
    float* __restrict__ ws, float* __restrict__ out)
{
  __shared__ int islast;
  int b = blockIdx.y;
  int n = blockIdx.x * 256 + (int)threadIdx.x;
  // mode(labels) from the 20 histogram partials; ties -> smallest index
  const int* cp = (const int*)(ws + WS_CNTP);
  int best = 0, bc = -1;
#pragma unroll
  for (int c = 0; c < 10; ++c) {
    int sc = 0;
#pragma unroll
    for (int p = 0; p < 20; ++p) sc += cp[p * 10 + c];
    if (sc > bc) { bc = sc; best = c; }
  }
  float kc = ws[WS_FMAX] * (-1.0f / (255.0f * 1000.0f));
  float wgt = 0.f, mk = 0.f;
  if (n < 20000) {
    float L1 = 0.f;
#pragma unroll
    for (int s2 = 0; s2 < 16; ++s2) L1 += l1p[(s2 * 32 + b) * 20096 + n];
    wgt = __expf(L1 * kc);
    if (labels[n] == best) mk = wgt;
  }
#pragma unroll
  for (int off = 32; off > 0; off >>= 1) {
    wgt += __shfl_xor(wgt, off);
    mk  += __shfl_xor(mk, off);
  }
  float* nrdr = ws + WS_NR;
  if ((threadIdx.x & 63) == 0) {
    atomicAdd(&nrdr[b], mk);
    atomicAdd(&nrdr[32 + b], wgt);
  }
  __syncthreads();                      // all 4 waves' atomics drained (vmcnt)
  if (threadIdx.x == 0) {
    __threadfence();
    int total = gridDim.x * gridDim.y;  // 79*32 = 2528
    islast = (atomicAdd((int*)ws + WS_CTR, 1) == total - 1) ? 1 : 0;
  }
  __syncthreads();
  if (islast && threadIdx.x < 32) {
    float nr = atomicAdd(&nrdr[threadIdx.x], 0.f);        // coherent read-back
    float dr = atomicAdd(&nrdr[32 + threadIdx.x], 0.f);
    out[threadIdx.x] = nr / dr;
  }
}

extern "C" void kernel_launch(void* const* d_in, const int* in_sizes, int n_in,
                              void* d_out, int out_size, void* d_ws, size_t ws_size,
                              hipStream_t stream)
{
  (void)in_sizes; (void)n_in; (void)out_size; (void)ws_size;
  const float* x    = (const float*)d_in[0];
  const float* w1   = (const float*)d_in[1];
  const float* c1b  = (const float*)d_in[2];
  const float* g1   = (const float*)d_in[3];
  const float* be1  = (const float*)d_in[4];
  const float* v1   = (const float*)d_in[6];
  const float* m1   = (const float*)d_in[5];
  const float* w2   = (const float*)d_in[7];
  const float* c2b  = (const float*)d_in[8];
  const float* g2   = (const float*)d_in[9];
  const float* be2  = (const float*)d_in[10];
  const float* m2   = (const float*)d_in[11];
  const float* v2   = (const float*)d_in[12];
  const float* nbrf = (const float*)d_in[13];
  const int* labels = (const int*)d_in[14];
  float* ws = (float*)d_ws;
  float* out = (float*)d_out;

  prep<<<309, 256, 0, stream>>>(labels, w2, c1b, g1, be1, m1, v1,
                                c2b, g2, be2, m2, v2, ws);
  k2_conv1<<<512, 256, 0, stream>>>(x, w1, ws, ws + WS_P1);
  k3_conv2<<<256, 256, 0, stream>>>(ws + WS_P1, ws + WS_W2T, ws, ws + WS_P2F, out, ws);
  k4_knn<<<dim3(157, 16), 256, 0, stream>>>(nbrf, ws + WS_P2F, ws, ws + WS_L1P);
  k5_final<<<dim3(79, 32), 256, 0, stream>>>(ws + WS_L1P, labels, ws, out);
}

// Round 14
// 360.678 us; speedup vs baseline: 1.3497x; 1.3497x over previous
//
#include <hip/hip_runtime.h>
#include <stdint.h>

// ---- workspace layout (float offsets) ----
#define WS_BN    0u        // A1[64] B1[64] A2[128] B2[128] = 384
#define WS_NR    384u      // nr[32] dr[32]
#define WS_FMAX  448u      // float (atomicMax as int)
#define WS_CTR   449u      // int ticket counter for k5 last-block
#define WS_CNTP  450u      // int[20][10] histogram partials (slot-written, no zero needed)
#define WS_P2F   768u      // [32][8192] f fp32 = 262144 (persistent through k4)
#define WS_X     262912u   // overlay:
#define WS_P1    WS_X                 // conv: [32][64][16][16] = 524288
#define WS_W2T   (WS_X + 524288u)     // conv: [9][64][128]     = 73728
#define WS_L1P   WS_X                 // knn:  [16][32][20096]  = 10289152

typedef float f4v __attribute__((ext_vector_type(4)));

__device__ __forceinline__ unsigned sad4(unsigned a, unsigned b, unsigned c) {
#if __has_builtin(__builtin_amdgcn_sad_u8)
  return __builtin_amdgcn_sad_u8(a, b, c);
#else
  unsigned d;
  asm("v_sad_u8 %0, %1, %2, %3" : "=v"(d) : "v"(a), "v"(b), "v"(c));
  return d;
#endif
}

__device__ __forceinline__ unsigned qpack(f4v v, float kq) {
  unsigned q0 = (unsigned)fmaf(v.x, kq, 0.5f);
  unsigned q1 = (unsigned)fmaf(v.y, kq, 0.5f);
  unsigned q2 = (unsigned)fmaf(v.z, kq, 0.5f);
  unsigned q3 = (unsigned)fmaf(v.w, kq, 0.5f);
  return q0 | (q1 << 8) | (q2 << 16) | (q3 << 24);
}

// ---------------- prep: BN fold + zeros | label histogram partials | w2t ----
__global__ __launch_bounds__(256) void prep(
    const int* __restrict__ labels, const float* __restrict__ w2,
    const float* __restrict__ c1b, const float* __restrict__ g1,
    const float* __restrict__ be1, const float* __restrict__ m1,
    const float* __restrict__ v1,
    const float* __restrict__ c2b, const float* __restrict__ g2,
    const float* __restrict__ be2, const float* __restrict__ m2,
    const float* __restrict__ v2,
    float* __restrict__ ws)
{
  int blk = blockIdx.x, tid = threadIdx.x;
  if (blk == 0) {
    if (tid < 64) {
      ws[WS_NR + tid] = 0.f;
      float A = g1[tid] * __frsqrt_rn(v1[tid] + 1e-5f);
      ws[WS_BN + tid] = A;
      ws[WS_BN + 64 + tid] = (c1b[tid] - m1[tid]) * A + be1[tid];
    } else if (tid < 192) {
      int c = tid - 64;
      float A = g2[c] * __frsqrt_rn(v2[c] + 1e-5f);
      ws[WS_BN + 128 + c] = A;
      ws[WS_BN + 256 + c] = (c2b[c] - m2[c]) * A + be2[c];
    } else if (tid == 192) {
      ws[WS_FMAX] = 2.0f;
    } else if (tid == 193) {
      ((int*)ws)[WS_CTR] = 0;
    }
  } else if (blk <= 20) {
    __shared__ int cnt[10];
    if (tid < 10) cnt[tid] = 0;
    __syncthreads();
    int base = (blk - 1) * 1000;
    for (int i = base + tid; i < base + 1000; i += 256)
      atomicAdd(&cnt[labels[i]], 1);
    __syncthreads();
    if (tid < 10) ((int*)(ws + WS_CNTP))[(blk - 1) * 10 + tid] = cnt[tid];
  } else {
    int idx = (blk - 21) * 256 + tid;
    if (idx < 73728) {
      int co = idx / 576, r = idx % 576, ci = r / 9, kk = r % 9;
      ws[WS_W2T + (kk * 64 + ci) * 128 + co] = w2[idx];
    }
  }
}

// ---------------- k2: conv1 + BN + ReLU + 2x2 maxpool ----------------
__global__ __launch_bounds__(256) void k2_conv1(
    const float* __restrict__ x, const float* __restrict__ w1,
    const float* __restrict__ wsc, float* __restrict__ p1)
{
  __shared__ float xs[3 * 34 * 34];
  int tid = threadIdx.x;
  int b = blockIdx.x >> 4, cog = blockIdx.x & 15;

  for (int idx = tid; idx < 3 * 34 * 34; idx += 256) {
    int ci = idx / 1156, r = idx % 1156, yy = r / 34, xc = r % 34;
    int yg = yy - 1, xg = xc - 1;
    float v = 0.f;
    if ((unsigned)yg < 32u && (unsigned)xg < 32u)
      v = x[((b * 3 + ci) * 32 + yg) * 32 + xg];
    xs[idx] = v;
  }
  __syncthreads();

  int py = tid >> 4, px = tid & 15;
  float acc[4][4] = {};
#pragma unroll
  for (int ci = 0; ci < 3; ++ci)
#pragma unroll
    for (int ky = 0; ky < 3; ++ky)
#pragma unroll
      for (int kx = 0; kx < 3; ++kx) {
        const float* xp = &xs[ci * 1156 + (2 * py + ky) * 34 + (2 * px + kx)];
        float i00 = xp[0], i01 = xp[1], i10 = xp[34], i11 = xp[35];
#pragma unroll
        for (int c = 0; c < 4; ++c) {
          float wv = w1[cog * 108 + c * 27 + ci * 9 + ky * 3 + kx];  // uniform -> s_load
          acc[c][0] = fmaf(i00, wv, acc[c][0]);
          acc[c][1] = fmaf(i01, wv, acc[c][1]);
          acc[c][2] = fmaf(i10, wv, acc[c][2]);
          acc[c][3] = fmaf(i11, wv, acc[c][3]);
        }
      }
#pragma unroll
  for (int c = 0; c < 4; ++c) {
    int co = cog * 4 + c;
    float A = wsc[WS_BN + co], B = wsc[WS_BN + 64 + co];
    float v0 = fmaxf(fmaf(acc[c][0], A, B), 0.f);
    float v1 = fmaxf(fmaf(acc[c][1], A, B), 0.f);
    float v2 = fmaxf(fmaf(acc[c][2], A, B), 0.f);
    float v3 = fmaxf(fmaf(acc[c][3], A, B), 0.f);
    float m = fmaxf(fmaxf(v0, v1), fmaxf(v2, v3));
    p1[((b * 64 + co) * 16 + py) * 16 + px] = m;
  }
}

// ---------------- k3: conv2 + BN + ReLU + pool + fused global fmax ----------------
__global__ __launch_bounds__(256) void k3_conv2(
    const float* __restrict__ p1, const float* __restrict__ w2t,
    const float* __restrict__ wsc, float* __restrict__ p2f,
    float* __restrict__ out, float* __restrict__ ws)
{
  __shared__ float in_s[32 * 324];  // 40.5 KB
  __shared__ float pb[4096];        // 16 KB pool buffer
  int tid = threadIdx.x;
  int b = blockIdx.x >> 3, cog = blockIdx.x & 7;
  int y = tid >> 4, xx = tid & 15;

  float acc[16];
#pragma unroll
  for (int c = 0; c < 16; ++c) acc[c] = 0.f;

  for (int h = 0; h < 2; ++h) {
    __syncthreads();
    for (int idx = tid; idx < 10368; idx += 256) {
      int ci = idx / 324, r = idx % 324, yy = r / 18, xc = r % 18;
      int yg = yy - 1, xg = xc - 1;
      float v = 0.f;
      if ((unsigned)yg < 16u && (unsigned)xg < 16u)
        v = p1[((b * 64 + h * 32 + ci) * 16 + yg) * 16 + xg];
      in_s[idx] = v;
    }
    __syncthreads();
    for (int ci = 0; ci < 32; ++ci) {
#pragma unroll
      for (int kk = 0; kk < 9; ++kk) {
        int ky = kk / 3, kx = kk % 3;
        float in = in_s[ci * 324 + (y + ky) * 18 + (xx + kx)];
        const float4* wp = (const float4*)(w2t + ((kk * 64 + h * 32 + ci) * 128 + cog * 16));
        float4 a0 = wp[0], a1 = wp[1], a2 = wp[2], a3 = wp[3];  // uniform -> s_load
        acc[0]  = fmaf(in, a0.x, acc[0]);  acc[1]  = fmaf(in, a0.y, acc[1]);
        acc[2]  = fmaf(in, a0.z, acc[2]);  acc[3]  = fmaf(in, a0.w, acc[3]);
        acc[4]  = fmaf(in, a1.x, acc[4]);  acc[5]  = fmaf(in, a1.y, acc[5]);
        acc[6]  = fmaf(in, a1.z, acc[6]);  acc[7]  = fmaf(in, a1.w, acc[7]);
        acc[8]  = fmaf(in, a2.x, acc[8]);  acc[9]  = fmaf(in, a2.y, acc[9]);
        acc[10] = fmaf(in, a2.z, acc[10]); acc[11] = fmaf(in, a2.w, acc[11]);
        acc[12] = fmaf(in, a3.x, acc[12]); acc[13] = fmaf(in, a3.y, acc[13]);
        acc[14] = fmaf(in, a3.z, acc[14]); acc[15] = fmaf(in, a3.w, acc[15]);
      }
    }
  }
  __syncthreads();
#pragma unroll
  for (int c = 0; c < 16; ++c) {
    int co = cog * 16 + c;
    float v = fmaxf(fmaf(acc[c], wsc[WS_BN + 128 + co], wsc[WS_BN + 256 + co]), 0.f);
    pb[c * 256 + y * 16 + xx] = v;
  }
  __syncthreads();
  if (tid < 64) {
    int py = tid >> 3, px = tid & 7;
    float lmax = 0.f;   // post-ReLU values >= 0
#pragma unroll
    for (int c = 0; c < 16; ++c) {
      const float* q = &pb[c * 256 + (2 * py) * 16 + 2 * px];
      float m = fmaxf(fmaxf(q[0], q[1]), fmaxf(q[16], q[17]));
      int co = cog * 16 + c;
      int fi = b * 8192 + co * 64 + py * 8 + px;
      p2f[fi] = m;
      out[32 + fi] = m;
      lmax = fmaxf(lmax, m);
    }
#pragma unroll
    for (int off = 32; off > 0; off >>= 1) lmax = fmaxf(lmax, __shfl_xor(lmax, off));
    if (tid == 0) atomicMax((int*)(ws + WS_FMAX), __float_as_int(lmax));
  }
}

// ---------------- k4: L1-kNN via v_sad_u8 — double-buffered async pipeline ----
// r13 diagnostic: k4_cold = 254 us = stage 142 (4.6 TB/s, BW fine) + compute
// 112, SERIAL (barrier drains vmcnt before every compute phase). Fix (T14):
// LDS double-buffer 2x(32KB n + 8KB f) = 80 KB (exactly 2 blocks/CU); chunk 1
// staging interleaved with chunk 0 compute in 4 sub-batches: issue 10 loads ->
// compute sub-phase g (buf0) -> qpack+write (buf1). Loads stay in flight under
// the ~600-cyc compute phase (10KB/wave x 8 waves/CU). One barrier per chunk.
// Peak live ~165 VGPR < 256 budget: NO occupancy attributes (r7/r11 lesson).
__global__ __launch_bounds__(256) void k4_knn(
    const float* __restrict__ nbr, const float* __restrict__ p2f,
    const float* __restrict__ wsc, float* __restrict__ l1p)
{
  __shared__ __align__(16) char smem[81920];   // nt0|nt1 (2x32KB), ft0|ft1 (2x8KB)
  const int tid = threadIdx.x;
  const int w = tid >> 6, lane = tid & 63;
  const int b_lane = lane & 3;    // 0..3
  const int n_lane = lane >> 2;   // 0..15
  const int n0 = blockIdx.x * 128;
  const int s = blockIdx.y;
  const float kq = 255.0f / wsc[WS_FMAX];
  const int wcol = (lane & 3) * 4;
  const int sl = lane >> 2;

  unsigned acc[8][8];
#pragma unroll
  for (int i = 0; i < 8; ++i)
#pragma unroll
    for (int j = 0; j < 8; ++j) acc[i][j] = 0u;

  // compute sub-phase g against buffers (nt, ft); accumulates into acc
  auto compute_g = [&](const char* nt, const char* ft, int g) {
    const int cs = w * 4 + g;
    uint4 fv[8];
#pragma unroll
    for (int i = 0; i < 8; ++i) {
      int row = b_lane + 4 * i;
      fv[i] = *(const uint4*)(ft + row * 256 + ((cs ^ (row & 15)) << 4));
    }
#pragma unroll
    for (int j = 0; j < 8; ++j) {
      int row = n_lane + 16 * j;
      uint4 nv = *(const uint4*)(nt + row * 256 + ((cs ^ (row & 15)) << 4));
#pragma unroll
      for (int i = 0; i < 8; ++i) {
        unsigned t0 = sad4(fv[i].x, nv.x, acc[i][j]);
        t0 = sad4(fv[i].y, nv.y, t0);
        t0 = sad4(fv[i].z, nv.z, t0);
        acc[i][j] = sad4(fv[i].w, nv.w, t0);
      }
    }
  };

  char* nt0 = smem;
  char* nt1 = smem + 32768;
  char* ft0 = smem + 65536;
  char* ft1 = smem + 65536 + 8192;
  const int dc0 = s * 512;
  const int dc1 = s * 512 + 256;

  // ---- prologue: stage chunk 0 -> buf0 (pipelined 4 batches of 10 loads) ----
#pragma unroll
  for (int g = 0; g < 4; ++g) {
    f4v nr[8], fr[2];
#pragma unroll
    for (int k = 0; k < 8; ++k) {
      int row = w * 32 + g * 8 + k;
      int nn = n0 + row; if (nn > 19999) nn = 19999;
      nr[k] = __builtin_nontemporal_load(
          (const f4v*)(nbr + (size_t)nn * 8192 + dc0 + lane * 4));
    }
#pragma unroll
    for (int k = 0; k < 2; ++k) {
      int row = w * 8 + g * 2 + k;
      fr[k] = *(const f4v*)(p2f + row * 8192 + dc0 + lane * 4);
    }
#pragma unroll
    for (int k = 0; k < 8; ++k) {
      int row = w * 32 + g * 8 + k;
      *(unsigned*)(nt0 + row * 256 + ((sl ^ (row & 15)) << 4) + wcol) = qpack(nr[k], kq);
    }
#pragma unroll
    for (int k = 0; k < 2; ++k) {
      int row = w * 8 + g * 2 + k;
      *(unsigned*)(ft0 + row * 256 + ((sl ^ (row & 15)) << 4) + wcol) = qpack(fr[k], kq);
    }
  }
  __syncthreads();

  // ---- chunk 0: compute buf0 || stage chunk 1 -> buf1 ----
#pragma unroll
  for (int g = 0; g < 4; ++g) {
    f4v nr[8], fr[2];
#pragma unroll
    for (int k = 0; k < 8; ++k) {        // issue early: in flight during compute
      int row = w * 32 + g * 8 + k;
      int nn = n0 + row; if (nn > 19999) nn = 19999;
      nr[k] = __builtin_nontemporal_load(
          (const f4v*)(nbr + (size_t)nn * 8192 + dc1 + lane * 4));
    }
#pragma unroll
    for (int k = 0; k < 2; ++k) {
      int row = w * 8 + g * 2 + k;
      fr[k] = *(const f4v*)(p2f + row * 8192 + dc1 + lane * 4);
    }
    compute_g(nt0, ft0, g);
#pragma unroll
    for (int k = 0; k < 8; ++k) {        // vmcnt waits land here, after compute
      int row = w * 32 + g * 8 + k;
      *(unsigned*)(nt1 + row * 256 + ((sl ^ (row & 15)) << 4) + wcol) = qpack(nr[k], kq);
    }
#pragma unroll
    for (int k = 0; k < 2; ++k) {
      int row = w * 8 + g * 2 + k;
      *(unsigned*)(ft1 + row * 256 + ((sl ^ (row & 15)) << 4) + wcol) = qpack(fr[k], kq);
    }
  }
  __syncthreads();

  // ---- chunk 1: compute buf1 ----
#pragma unroll
  for (int g = 0; g < 4; ++g) compute_g(nt1, ft1, g);

  // cross-wave reduce, 2 halves of 16 b-rows (32 KB overlay aliases nt0)
  unsigned* red = (unsigned*)smem;
#pragma unroll
  for (int r = 0; r < 2; ++r) {
    __syncthreads();
#pragma unroll
    for (int ii = 0; ii < 4; ++ii) {
#pragma unroll
      for (int j = 0; j < 8; ++j) {
        int b16 = b_lane + 4 * ii;            // 0..15 within this half
        int n = n_lane + 16 * j;
        red[(b16 * 128 + n) * 4 + w] = acc[r * 4 + ii][j];
      }
    }
    __syncthreads();
#pragma unroll
    for (int k = 0; k < 8; ++k) {
      int e = k * 256 + tid;                  // 0..2047
      uint4 v = *(const uint4*)(red + e * 4);
      int b = 16 * r + (e >> 7), n = e & 127;
      l1p[(s * 32 + b) * 20096 + n0 + n] = (float)(v.x + v.y + v.z + v.w);
    }
  }
}

// ---------------- k5: reduce splits, exp-weight, mask, last-block finalize ----
__global__ __launch_bounds__(256) void k5_final(
    const float* __restrict__ l1p, const int* __restrict__ labels,
    float* __restrict__ ws, float* __restrict__ out)
{
  __shared__ int islast;
  int b = blockIdx.y;
  int n = blockIdx.x * 256 + (int)threadIdx.x;
  // mode(labels) from the 20 histogram partials; ties -> smallest index
  const int* cp = (const int*)(ws + WS_CNTP);
  int best = 0, bc = -1;
#pragma unroll
  for (int c = 0; c < 10; ++c) {
    int sc = 0;
#pragma unroll
    for (int p = 0; p < 20; ++p) sc += cp[p * 10 + c];
    if (sc > bc) { bc = sc; best = c; }
  }
  float kc = ws[WS_FMAX] * (-1.0f / (255.0f * 1000.0f));
  float wgt = 0.f, mk = 0.f;
  if (n < 20000) {
    float L1 = 0.f;
#pragma unroll
    for (int s2 = 0; s2 < 16; ++s2) L1 += l1p[(s2 * 32 + b) * 20096 + n];
    wgt = __expf(L1 * kc);
    if (labels[n] == best) mk = wgt;
  }
#pragma unroll
  for (int off = 32; off > 0; off >>= 1) {
    wgt += __shfl_xor(wgt, off);
    mk  += __shfl_xor(mk, off);
  }
  float* nrdr = ws + WS_NR;
  if ((threadIdx.x & 63) == 0) {
    atomicAdd(&nrdr[b], mk);
    atomicAdd(&nrdr[32 + b], wgt);
  }
  __syncthreads();                      // all 4 waves' atomics drained (vmcnt)
  if (threadIdx.x == 0) {
    __threadfence();
    int total = gridDim.x * gridDim.y;  // 79*32 = 2528
    islast = (atomicAdd((int*)ws + WS_CTR, 1) == total - 1) ? 1 : 0;
  }
  __syncthreads();
  if (islast && threadIdx.x < 32) {
    float nr = atomicAdd(&nrdr[threadIdx.x], 0.f);        // coherent read-back
    float dr = atomicAdd(&nrdr[32 + threadIdx.x], 0.f);
    out[threadIdx.x] = nr / dr;
  }
}

extern "C" void kernel_launch(void* const* d_in, const int* in_sizes, int n_in,
                              void* d_out, int out_size, void* d_ws, size_t ws_size,
                              hipStream_t stream)
{
  (void)in_sizes; (void)n_in; (void)out_size; (void)ws_size;
  const float* x    = (const float*)d_in[0];
  const float* w1   = (const float*)d_in[1];
  const float* c1b  = (const float*)d_in[2];
  const float* g1   = (const float*)d_in[3];
  const float* be1  = (const float*)d_in[4];
  const float* m1   = (const float*)d_in[5];
  const float* v1   = (const float*)d_in[6];
  const float* w2   = (const float*)d_in[7];
  const float* c2b  = (const float*)d_in[8];
  const float* g2   = (const float*)d_in[9];
  const float* be2  = (const float*)d_in[10];
  const float* m2   = (const float*)d_in[11];
  const float* v2   = (const float*)d_in[12];
  const float* nbrf = (const float*)d_in[13];
  const int* labels = (const int*)d_in[14];
  float* ws = (float*)d_ws;
  float* out = (float*)d_out;

  prep<<<309, 256, 0, stream>>>(labels, w2, c1b, g1, be1, m1, v1,
                                c2b, g2, be2, m2, v2, ws);
  k2_conv1<<<512, 256, 0, stream>>>(x, w1, ws, ws + WS_P1);
  k3_conv2<<<256, 256, 0, stream>>>(ws + WS_P1, ws + WS_W2T, ws, ws + WS_P2F, out, ws);
  k4_knn<<<dim3(157, 16), 256, 0, stream>>>(nbrf, ws + WS_P2F, ws, ws + WS_L1P);
  k5_final<<<dim3(79, 32), 256, 0, stream>>>(ws + WS_L1P, labels, ws, out);
}